// Round 6
// baseline (92.858 us; speedup 1.0000x reference)
//
#include <hip/hip_runtime.h>

#define MDEPTH 5
#define TPB 256
#define LDS_STRIDE 19   // 18 floats/row + 1 pad -> odd stride, ~conflict-free

__global__ __launch_bounds__(TPB) void memtap_kernel(
    const float* __restrict__ iq, float* __restrict__ out,
    int B, int S, int T)
{
    const int blocksPerB = (T + TPB - 1) / TPB;
    const int b  = blockIdx.x / blocksPerB;
    const int t0 = (blockIdx.x % blocksPerB) * TPB;
    const int tid = threadIdx.x;

    __shared__ float lds[TPB * LDS_STRIDE];

    const int t = t0 + tid;
    if (t < T) {
        const int n = t + MDEPTH;                        // n in [5, S-1]
        const float2* iqb = (const float2*)iq + (size_t)b * S;

        float2 v[MDEPTH + 1];
        #pragma unroll
        for (int k = 0; k <= MDEPTH; ++k) v[k] = iqb[n - k];   // v[k] = iq(n-k)

        float* o = &lds[tid * LDS_STRIDE];
        o[0] = v[0].x;                                   // current_iq
        o[1] = v[0].y;
        #pragma unroll
        for (int k = 0; k <= MDEPTH; ++k)                // env(n-k), k=0..5
            o[2 + k] = sqrtf(v[k].x * v[k].x + v[k].y * v[k].y);
        #pragma unroll
        for (int j = 0; j < MDEPTH; ++j) {               // iq(n-1-j), interleaved
            o[8 + 2 * j] = v[j + 1].x;
            o[9 + 2 * j] = v[j + 1].y;
        }
    }
    __syncthreads();

    // Phase 2: coalesced float2 stores of the block's contiguous region.
    // f-th float2 of region = row r = f/9, col pair c = f%9. Incremental:
    // f += 256  =>  c += 4, r += 28, plus wrap (256 = 9*28 + 4).
    const int cnt = min(TPB, T - t0);        // valid rows in this block
    const int nf2 = cnt * 9;                 // float2 elements (18 floats/row)
    float2* ob = (float2*)out + ((size_t)b * T + t0) * 9;

    int r = tid / 9;                         // one-time magic div
    int c = tid - 9 * r;
    for (int f = tid; f < nf2; f += TPB) {
        float2 w = make_float2(lds[r * LDS_STRIDE + 2 * c],
                               lds[r * LDS_STRIDE + 2 * c + 1]);
        // non-temporal 8B store: write-once stream, don't pollute L2
        __builtin_nontemporal_store(*(const double*)&w, (double*)(ob + f));
        c += 4; r += 28;
        if (c >= 9) { c -= 9; r += 1; }
    }
}

extern "C" void kernel_launch(void* const* d_in, const int* in_sizes, int n_in,
                              void* d_out, int out_size, void* d_ws, size_t ws_size,
                              hipStream_t stream) {
    (void)in_sizes; (void)n_in; (void)d_ws; (void)ws_size; (void)out_size;
    const float* iq = (const float*)d_in[0];
    float* out = (float*)d_out;

    const int B = 64, S = 16384;
    const int T = S - MDEPTH;                     // 16379
    const int blocksPerB = (T + TPB - 1) / TPB;   // 64
    const int grid = B * blocksPerB;              // 4096

    memtap_kernel<<<grid, TPB, 0, stream>>>(iq, out, B, S, T);
}